// Round 1
// baseline (471.660 us; speedup 1.0000x reference)
//
#include <hip/hip_runtime.h>
#include <hip/hip_bf16.h>
#include <math.h>

// Problem constants (fixed by the reference's setup_inputs)
#define BB 4
#define TT 2048
#define DD 384
#define HH 192
#define TOTAL_LEN 65536                 // B*T*8 (static output length)
#define EXP_ELEMS (BB * TOTAL_LEN * DD) // 100,663,296 floats
#define F4_PER_ROW (DD / 4)             // 96
#define TOTAL_F4 (BB * TOTAL_LEN * F4_PER_ROW) // 25,165,824

// ---------------------------------------------------------------------------
// K1: 2-layer MLP duration head.
// grid 256 x block 256. Each wave handles 8 rows; lane owns h-columns
// {lane, lane+64, lane+128}. x loads are wave-uniform (row from
// readfirstlane(wave), k from loop) -> compiler emits s_load; w1 loads are
// lane-consecutive -> coalesced.
// ---------------------------------------------------------------------------
__global__ __launch_bounds__(256) void mlp_dur_kernel(
    const float* __restrict__ x, const float* __restrict__ w1,
    const float* __restrict__ b1, const float* __restrict__ w2,
    const float* __restrict__ b2, float* __restrict__ dur_out,
    int* __restrict__ dur0) {
  const int lane = threadIdx.x & 63;
  const int wave = __builtin_amdgcn_readfirstlane(threadIdx.x >> 6);
  const int row0 = (blockIdx.x * 4 + wave) * 8;
  const int j0 = lane, j1 = lane + 64, j2 = lane + 128;

  float acc[8][3];
#pragma unroll
  for (int r = 0; r < 8; ++r) {
    acc[r][0] = 0.f; acc[r][1] = 0.f; acc[r][2] = 0.f;
  }

  for (int k = 0; k < DD; k += 4) {
    float wa[4], wb[4], wc[4];
#pragma unroll
    for (int kk = 0; kk < 4; ++kk) {
      const float* wrow = w1 + (size_t)(k + kk) * HH;
      wa[kk] = wrow[j0];
      wb[kk] = wrow[j1];
      wc[kk] = wrow[j2];
    }
#pragma unroll
    for (int r = 0; r < 8; ++r) {
      const float* xrow = x + (size_t)(row0 + r) * DD + k; // wave-uniform
#pragma unroll
      for (int kk = 0; kk < 4; ++kk) {
        const float xv = xrow[kk]; // uniform -> s_load, SGPR operand in fma
        acc[r][0] = fmaf(xv, wa[kk], acc[r][0]);
        acc[r][1] = fmaf(xv, wb[kk], acc[r][1]);
        acc[r][2] = fmaf(xv, wc[kk], acc[r][2]);
      }
    }
  }

  const float b10 = b1[j0], b11 = b1[j1], b12 = b1[j2];
  const float w20 = w2[j0], w21 = w2[j1], w22 = w2[j2];
  const float bias2 = b2[0];

#pragma unroll
  for (int r = 0; r < 8; ++r) {
    float s = fmaxf(acc[r][0] + b10, 0.f) * w20 +
              fmaxf(acc[r][1] + b11, 0.f) * w21 +
              fmaxf(acc[r][2] + b12, 0.f) * w22;
#pragma unroll
    for (int off = 32; off > 0; off >>= 1) s += __shfl_down(s, off, 64);
    if (lane == 0) {
      const float z = s + bias2;
      // numerically stable softplus
      const float sp = fmaxf(z, 0.f) + log1pf(expf(-fabsf(z)));
      const float dur = rintf(fmaxf(sp, 8.0f)); // round-half-even == jnp.round
      const int row = row0 + r;
      dur_out[row] = dur;
      if (row < TT) dur0[row] = (int)dur; // batch-0 durations drive expansion
    }
  }
}

// ---------------------------------------------------------------------------
// K2: inclusive scan of dur0[2048] -> cum[2048]. One block, 256 threads x 8.
// ---------------------------------------------------------------------------
__global__ __launch_bounds__(256) void scan_kernel(const int* __restrict__ dur0,
                                                   int* __restrict__ cum) {
  __shared__ int lds[256];
  const int tid = threadIdx.x;
  const int base = tid * 8;
  int v[8];
  int run = 0;
#pragma unroll
  for (int i = 0; i < 8; ++i) {
    run += dur0[base + i];
    v[i] = run;
  }
  lds[tid] = run;
  __syncthreads();
  for (int off = 1; off < 256; off <<= 1) {
    const int t = (tid >= off) ? lds[tid - off] : 0;
    __syncthreads();
    lds[tid] += t;
    __syncthreads();
  }
  const int excl = lds[tid] - run;
#pragma unroll
  for (int i = 0; i < 8; ++i) cum[base + i] = v[i] + excl;
}

// ---------------------------------------------------------------------------
// K3: idx_map[pos] = searchsorted(cum, pos, 'right') if pos < cum[-1] else -1
// grid 256 x block 256 (65536 positions); cum is L2/L1-hot (8 KB).
// ---------------------------------------------------------------------------
__global__ __launch_bounds__(256) void idx_kernel(const int* __restrict__ cum,
                                                  int* __restrict__ idx_map) {
  const int pos = blockIdx.x * 256 + threadIdx.x;
  const int total = cum[TT - 1];
  int lo = 0, hi = TT - 1; // smallest t with cum[t] > pos
  while (lo < hi) {
    const int mid = (lo + hi) >> 1;
    if (cum[mid] > pos) hi = mid;
    else lo = mid + 1;
  }
  idx_map[pos] = (pos < total) ? lo : -1;
}

// ---------------------------------------------------------------------------
// K4: expansion. One float4 (16 B) per lane, fully coalesced stores.
// out[b, pos, :] = (idx_map[pos] >= 0) ? x[b, idx_map[pos], :] : 0
// ---------------------------------------------------------------------------
__global__ __launch_bounds__(256) void expand_kernel(
    const float4* __restrict__ x4, const int* __restrict__ idx_map,
    float4* __restrict__ out4) {
  const unsigned t = blockIdx.x * 256u + threadIdx.x;
  const unsigned row = t / 96u;       // magic-mul division
  const unsigned col = t - row * 96u;
  const unsigned b = row >> 16;       // TOTAL_LEN = 65536
  const unsigned pos = row & 65535u;
  const int id = idx_map[pos]; // 96 lanes share one entry -> L1 broadcast
  float4 v = {0.f, 0.f, 0.f, 0.f};
  if (id >= 0) v = x4[((size_t)b * TT + (unsigned)id) * F4_PER_ROW + col];
  out4[t] = v;
}

extern "C" void kernel_launch(void* const* d_in, const int* in_sizes, int n_in,
                              void* d_out, int out_size, void* d_ws,
                              size_t ws_size, hipStream_t stream) {
  const float* x = (const float*)d_in[0];
  const float* w1 = (const float*)d_in[1];
  const float* b1 = (const float*)d_in[2];
  const float* w2 = (const float*)d_in[3];
  const float* b2 = (const float*)d_in[4];
  // d_in[5] = total_length scalar; static (65536) by construction.

  float* out = (float*)d_out;
  float* dur_out = out + (size_t)EXP_ELEMS; // output 1: (B, T) durations

  int* ws = (int*)d_ws;
  int* dur0 = ws;            // 2048 ints
  int* cum = ws + TT;        // 2048 ints
  int* idx_map = ws + 2 * TT; // 65536 ints   (total: ~276 KB of ws)

  mlp_dur_kernel<<<256, 256, 0, stream>>>(x, w1, b1, w2, b2, dur_out, dur0);
  scan_kernel<<<1, 256, 0, stream>>>(dur0, cum);
  idx_kernel<<<TOTAL_LEN / 256, 256, 0, stream>>>(cum, idx_map);
  expand_kernel<<<TOTAL_F4 / 256, 256, 0, stream>>>((const float4*)x, idx_map,
                                                    (float4*)out);
}

// Round 3
// 452.028 us; speedup vs baseline: 1.0434x; 1.0434x over previous
//
#include <hip/hip_runtime.h>
#include <hip/hip_bf16.h>
#include <math.h>

// Problem constants (fixed by the reference's setup_inputs)
#define BB 4
#define TT 2048
#define DD 384
#define HH 192
#define TOTAL_LEN 65536                 // B*T*8 (static output length)
#define EXP_ELEMS (BB * TOTAL_LEN * DD) // 100,663,296 floats
#define F4_PER_ROW (DD / 4)             // 96
#define TOTAL_F4 (BB * TOTAL_LEN * F4_PER_ROW) // 25,165,824
#define ROWS_PER_BLK 16

typedef float f32x4 __attribute__((ext_vector_type(4))); // clang vector: ok for nontemporal builtins

// ---------------------------------------------------------------------------
// K1: 2-layer MLP duration head, spill-proof layout.
// 512 blocks x 256 threads; block stages 16 x-rows in LDS (24 KB).
// Thread j<192 owns h-column j: acc[16] registers, w1 reads coalesced
// (thread j -> w1[k*192+j]) and shared across the 16 rows. LDS x reads are
// wave-uniform -> broadcast (no bank conflicts). Register budget ~40 VGPRs:
// no spill possible. 2 blocks/CU -> 8 waves/CU.
// ---------------------------------------------------------------------------
__global__ __launch_bounds__(256) void mlp_dur_kernel(
    const float* __restrict__ x, const float* __restrict__ w1,
    const float* __restrict__ b1, const float* __restrict__ w2,
    const float* __restrict__ b2, float* __restrict__ dur_out,
    int* __restrict__ dur0) {
  __shared__ float xs[ROWS_PER_BLK * DD]; // 24 KB
  __shared__ float part[ROWS_PER_BLK * 4];

  const int tid = threadIdx.x;
  const int lane = tid & 63;
  const int wave = tid >> 6;
  const int row0 = blockIdx.x * ROWS_PER_BLK;

  // Stage 16 rows (1536 float4) coalesced into LDS.
  const f32x4* xg = (const f32x4*)(x + (size_t)row0 * DD);
  f32x4* xs4 = (f32x4*)xs;
#pragma unroll
  for (int i = 0; i < 6; ++i) xs4[i * 256 + tid] = xg[i * 256 + tid];
  __syncthreads();

  float acc[ROWS_PER_BLK];
#pragma unroll
  for (int r = 0; r < ROWS_PER_BLK; ++r) acc[r] = 0.f;

  const int j = tid;
  if (j < HH) {
    for (int k = 0; k < DD; k += 4) {
      float w[4];
#pragma unroll
      for (int kk = 0; kk < 4; ++kk) w[kk] = w1[(size_t)(k + kk) * HH + j];
#pragma unroll
      for (int r = 0; r < ROWS_PER_BLK; ++r) {
        const float* xr = xs + r * DD + k;
#pragma unroll
        for (int kk = 0; kk < 4; ++kk) acc[r] = fmaf(xr[kk], w[kk], acc[r]);
      }
    }
  }

  // Phase 2: p[r] = relu(acc[r]+b1[j]) * w2[j]; reduce over j across block.
  const float b1v = (j < HH) ? b1[j] : 0.f;
  const float w2v = (j < HH) ? w2[j] : 0.f;

#pragma unroll
  for (int r = 0; r < ROWS_PER_BLK; ++r) {
    float s = fmaxf(acc[r] + b1v, 0.f) * w2v; // j>=192: acc=0,w2v=0 -> 0
#pragma unroll
    for (int off = 32; off > 0; off >>= 1) s += __shfl_down(s, off, 64);
    if (lane == 0) part[r * 4 + wave] = s;
  }
  __syncthreads();

  if (tid < ROWS_PER_BLK) {
    const float z = part[tid * 4] + part[tid * 4 + 1] + part[tid * 4 + 2] +
                    part[tid * 4 + 3] + b2[0];
    const float sp = fmaxf(z, 0.f) + log1pf(expf(-fabsf(z))); // stable softplus
    const float dur = rintf(fmaxf(sp, 8.0f)); // round-half-even == jnp.round
    const int row = row0 + tid;
    dur_out[row] = dur;
    if (row < TT) dur0[row] = (int)dur; // batch-0 durations drive expansion
  }
}

// ---------------------------------------------------------------------------
// K2: inclusive scan of dur0[2048] -> cum[2048]. One block, 256 threads x 8.
// ---------------------------------------------------------------------------
__global__ __launch_bounds__(256) void scan_kernel(const int* __restrict__ dur0,
                                                   int* __restrict__ cum) {
  __shared__ int lds[256];
  const int tid = threadIdx.x;
  const int base = tid * 8;
  int v[8];
  int run = 0;
#pragma unroll
  for (int i = 0; i < 8; ++i) {
    run += dur0[base + i];
    v[i] = run;
  }
  lds[tid] = run;
  __syncthreads();
  for (int off = 1; off < 256; off <<= 1) {
    const int t = (tid >= off) ? lds[tid - off] : 0;
    __syncthreads();
    lds[tid] += t;
    __syncthreads();
  }
  const int excl = lds[tid] - run;
#pragma unroll
  for (int i = 0; i < 8; ++i) cum[base + i] = v[i] + excl;
}

// ---------------------------------------------------------------------------
// K3: idx_map[pos] = searchsorted(cum, pos, 'right') if pos < cum[-1] else -1
// ---------------------------------------------------------------------------
__global__ __launch_bounds__(256) void idx_kernel(const int* __restrict__ cum,
                                                  int* __restrict__ idx_map) {
  const int pos = blockIdx.x * 256 + threadIdx.x;
  const int total = cum[TT - 1];
  int lo = 0, hi = TT - 1; // smallest t with cum[t] > pos
  while (lo < hi) {
    const int mid = (lo + hi) >> 1;
    if (cum[mid] > pos) hi = mid;
    else lo = mid + 1;
  }
  idx_map[pos] = (pos < total) ? lo : -1;
}

// ---------------------------------------------------------------------------
// K4: expansion. One float4 (16 B) per lane, coalesced nontemporal stores.
// out[b, pos, :] = (idx_map[pos] >= 0) ? x[b, idx_map[pos], :] : 0
// ---------------------------------------------------------------------------
__global__ __launch_bounds__(256) void expand_kernel(
    const f32x4* __restrict__ x4, const int* __restrict__ idx_map,
    f32x4* __restrict__ out4) {
  const unsigned t = blockIdx.x * 256u + threadIdx.x;
  const unsigned row = t / 96u;       // magic-mul division
  const unsigned col = t - row * 96u;
  const unsigned b = row >> 16;       // TOTAL_LEN = 65536
  const unsigned pos = row & 65535u;
  const int id = idx_map[pos]; // broadcast across the 96 lanes of a row
  f32x4 v = {0.f, 0.f, 0.f, 0.f};
  if (id >= 0) v = x4[((size_t)b * TT + (unsigned)id) * F4_PER_ROW + col];
  __builtin_nontemporal_store(v, out4 + t);
}

extern "C" void kernel_launch(void* const* d_in, const int* in_sizes, int n_in,
                              void* d_out, int out_size, void* d_ws,
                              size_t ws_size, hipStream_t stream) {
  const float* x = (const float*)d_in[0];
  const float* w1 = (const float*)d_in[1];
  const float* b1 = (const float*)d_in[2];
  const float* w2 = (const float*)d_in[3];
  const float* b2 = (const float*)d_in[4];
  // d_in[5] = total_length scalar; static (65536) by construction.

  float* out = (float*)d_out;
  float* dur_out = out + (size_t)EXP_ELEMS; // output 1: (B, T) durations

  int* ws = (int*)d_ws;
  int* dur0 = ws;             // 2048 ints
  int* cum = ws + TT;         // 2048 ints
  int* idx_map = ws + 2 * TT; // 65536 ints

  mlp_dur_kernel<<<512, 256, 0, stream>>>(x, w1, b1, w2, b2, dur_out, dur0);
  scan_kernel<<<1, 256, 0, stream>>>(dur0, cum);
  idx_kernel<<<TOTAL_LEN / 256, 256, 0, stream>>>(cum, idx_map);
  expand_kernel<<<TOTAL_F4 / 256, 256, 0, stream>>>((const f32x4*)x, idx_map,
                                                    (f32x4*)out);
}